// Round 5
// baseline (491.742 us; speedup 1.0000x reference)
//
#include <hip/hip_runtime.h>
#include <hip/hip_bf16.h>
#include <stdint.h>

typedef __attribute__((ext_vector_type(8))) short short8;
typedef __attribute__((ext_vector_type(4))) float floatx4;
typedef unsigned short u16;

#define IN_DIM  1024
#define OUT_DIM 1024
#define NG      11            // spline bases per channel
#define GK      12            // + silu slot
#define KDIM    (IN_DIM * GK) // 12288
#define TOKENS  8192
#define BK      64            // K-tile: 2 mfma k-steps

__device__ __forceinline__ u16 f2bf(float f) {
  uint32_t u = __float_as_uint(f);
  uint32_t r = (u + 0x7fffu + ((u >> 16) & 1u)) >> 16;  // RNE
  return (u16)r;
}

// ---------------- pack Wt: bf16 [OUT_DIM][KDIM]; group i: coeff[o][i][0..10]*ss, scale_base[o][i]
// Coalesced: block stages its 2816 coeff floats via 11 stride-256 dword loads into LDS,
// then per-thread convert, b64 LDS stage, uint4 coalesced global stores.
__global__ __launch_bounds__(256) void pack_wt_kernel(
    const float* __restrict__ coeff, const float* __restrict__ sb,
    const float* __restrict__ ss_p, u16* __restrict__ Wt)
{
  __shared__ float cf[256 * NG];               // 11264 B
  __shared__ __align__(16) u16 st[256 * GK];   // 6144 B
  const int tid = threadIdx.x;
  const int b   = blockIdx.x;                  // 4096 blocks; one block = one o, 256 consecutive i
  const int o   = b >> 2;
  const int i0  = (b & 3) * 256;
  const float* cbase = coeff + (size_t)o * (IN_DIM * NG) + (size_t)i0 * NG;  // 2816 floats contiguous
#pragma unroll
  for (int p = 0; p < NG; ++p) cf[p * 256 + tid] = cbase[p * 256 + tid];
  const float ss  = ss_p[0];
  const float sbv = sb[(size_t)o * IN_DIM + i0 + tid];
  __syncthreads();
  const float* cp = cf + tid * NG;             // bank stride 11 (odd) -> 2-way, free
  u16 h[GK];
#pragma unroll
  for (int g = 0; g < NG; ++g) h[g] = f2bf(cp[g] * ss);
  h[NG] = f2bf(sbv);
  uint64_t V0 = (uint64_t)h[0] | ((uint64_t)h[1] << 16) | ((uint64_t)h[2] << 32) | ((uint64_t)h[3] << 48);
  uint64_t V1 = (uint64_t)h[4] | ((uint64_t)h[5] << 16) | ((uint64_t)h[6] << 32) | ((uint64_t)h[7] << 48);
  uint64_t V2 = (uint64_t)h[8] | ((uint64_t)h[9] << 16) | ((uint64_t)h[10] << 32) | ((uint64_t)h[11] << 48);
  uint64_t* sp = (uint64_t*)(st + tid * GK);
  sp[0] = V0; sp[1] = V1; sp[2] = V2;
  __syncthreads();
  const uint4* src = (const uint4*)st;         // 384 uint4
  uint4* dst = (uint4*)(Wt + (size_t)b * (256 * GK));
  dst[tid] = src[tid];
  if (tid < 128) dst[256 + tid] = src[256 + tid];
}

// ---------------- expand: closed-form cubic B-spline (uniform grid), register funnel placement,
// LDS-staged coalesced stores. (Verified R4: absmax 0.125.)
__global__ __launch_bounds__(256) void expand_kernel(
    const float* __restrict__ X, const float* __restrict__ grid,
    u16* __restrict__ A, int m0)
{
  __shared__ __align__(16) u16 st[256 * GK];
  int tid = threadIdx.x;
  int idx = blockIdx.x * 256 + tid;
  float x = X[(size_t)m0 * IN_DIM + idx];

  const float g0    = grid[0];
  const float inv_h = 1.0f / (grid[1] - grid[0]);

  float t  = (x - g0) * inv_h;
  float fc = floorf(t);
  int   c  = (int)fc;
  float u  = t - fc;
  float u2 = u * u;
  float w1 = 1.0f - u;
  float b0 = (w1 * w1 * w1) * (1.0f / 6.0f);
  float b1 = (0.5f * u - 1.0f) * u2 + (2.0f / 3.0f);
  float b2 = ((-0.5f * u + 0.5f) * u + 0.5f) * u + (1.0f / 6.0f);
  float b3 = (u2 * u) * (1.0f / 6.0f);
  float sil = x / (1.0f + __expf(-x));

  uint64_t P = (uint64_t)f2bf(b0) | ((uint64_t)f2bf(b1) << 16)
             | ((uint64_t)f2bf(b2) << 32) | ((uint64_t)f2bf(b3) << 48);
  int  k  = c - 3;
  bool cv = (c >= 0) && (c <= 13);
  int  kneg = (k < 0) ? -k : 0;
  uint64_t Pc = cv ? (P >> (16 * kneg)) : 0ull;
  uint32_t sh = (uint32_t)(16 * ((k < 0) ? 0 : k));

  uint64_t V0 = (sh < 64)  ? (Pc << (sh & 63)) : 0ull;
  uint64_t V1 = (sh == 0)  ? 0ull :
                (sh < 64)  ? (Pc >> ((64 - sh) & 63)) :
                (sh < 128) ? (Pc << ((sh - 64) & 63)) : 0ull;
  uint64_t V2 = (sh <= 64) ? 0ull :
                (sh < 128) ? (Pc >> ((128 - sh) & 63)) :
                             (Pc << ((sh - 128) & 63));
  V2 = (V2 & 0x0000FFFFFFFFFFFFull) | ((uint64_t)f2bf(sil) << 48);

  uint64_t* sp = (uint64_t*)(st + tid * GK);
  sp[0] = V0; sp[1] = V1; sp[2] = V2;
  __syncthreads();

  const uint4* src = (const uint4*)st;
  uint4* dst = (uint4*)(A + (size_t)blockIdx.x * (256 * GK));
  dst[tid] = src[tid];
  if (tid < 128) dst[256 + tid] = src[256 + tid];
}

// ---------------- GEMM (R4 structure + split-K for occupancy)
__device__ __forceinline__ void async16(const u16* g, u16* l) {
  __builtin_amdgcn_global_load_lds(
      (const __attribute__((address_space(1))) uint32_t*)g,
      (__attribute__((address_space(3))) uint32_t*)l,
      16, 0, 0);
}

// grid = mtiles * 8 * nsplit. Split s covers K range [s*k_iters*BK, ...). s=0 -> out, s=1 -> part.
// blockIdx ≡ bm (mod 8) for all (bn,s) -> A-strip stays XCD-local (R4: FETCH 197 MB, conflicts 0).
__global__ __launch_bounds__(256) void gemm_kernel(
    const u16* __restrict__ A, const u16* __restrict__ Wt,
    float* __restrict__ out, float* __restrict__ part,
    int m0, int mtiles, int k_iters)
{
  __shared__ __align__(16) u16 As[128 * BK];   // 16 KB
  __shared__ __align__(16) u16 Bs[128 * BK];   // 16 KB

  const int tid  = threadIdx.x;
  const int lane = tid & 63;
  const int wave = tid >> 6;
  const int mt8  = mtiles * 8;
  const int s    = blockIdx.x / mt8;
  const int r    = blockIdx.x - s * mt8;
  const int bm   = r % mtiles;
  const int bn   = r / mtiles;
  const int kb   = s * k_iters * BK;
  const int wm = (wave >> 1) * 64;
  const int wn = (wave & 1) * 64;

  floatx4 acc[4][4];
#pragma unroll
  for (int a = 0; a < 4; ++a)
#pragma unroll
    for (int b = 0; b < 4; ++b) acc[a][b] = (floatx4){0.f, 0.f, 0.f, 0.f};

  const int srow  = lane >> 3;
  const int gamma = (lane & 7) ^ srow;
  const u16* Ag = A  + (size_t)(bm * 128 + wave * 32 + srow) * KDIM + kb + gamma * 8;
  const u16* Bg = Wt + (size_t)(bn * 128 + wave * 32 + srow) * KDIM + kb + gamma * 8;
  u16* Al = As + (wave * 32) * BK;
  u16* Bl = Bs + (wave * 32) * BK;

  const int quad = lane >> 4;
  const int l16  = lane & 15;
  const int sw   = l16 & 7;

  for (int it = 0; it < k_iters; ++it) {
    const int k0 = it * BK;
#pragma unroll
    for (int op = 0; op < 4; ++op) {
      async16(Ag + k0 + (size_t)(op * 8) * KDIM, Al + op * 8 * BK);
      async16(Bg + k0 + (size_t)(op * 8) * KDIM, Bl + op * 8 * BK);
    }
    __syncthreads();

    short8 af[4][2], bf[4][2];
#pragma unroll
    for (int ss = 0; ss < 4; ++ss)
#pragma unroll
      for (int t = 0; t < 2; ++t) {
        int cc = (t * 4 + quad) ^ sw;
        af[ss][t] = *(const short8*)&As[(wm + ss * 16 + l16) * BK + cc * 8];
        bf[ss][t] = *(const short8*)&Bs[(wn + ss * 16 + l16) * BK + cc * 8];
      }

#pragma unroll
    for (int sm = 0; sm < 4; ++sm)
#pragma unroll
      for (int sn = 0; sn < 4; ++sn)
#pragma unroll
        for (int t = 0; t < 2; ++t)
          acc[sm][sn] = __builtin_amdgcn_mfma_f32_16x16x32_bf16(af[sm][t], bf[sn][t], acc[sm][sn], 0, 0, 0);

    __syncthreads();
  }

  float* op = (s == 0) ? out : part;
#pragma unroll
  for (int sm = 0; sm < 4; ++sm)
#pragma unroll
    for (int sn = 0; sn < 4; ++sn) {
      int row0 = m0 + bm * 128 + wm + sm * 16 + quad * 4;
      int col  = bn * 128 + wn + sn * 16 + l16;
#pragma unroll
      for (int rr = 0; rr < 4; ++rr)
        op[(size_t)(row0 + rr) * OUT_DIM + col] = acc[sm][sn][rr];
    }
}

// out += part, float4-vectorized
__global__ __launch_bounds__(256) void reduce_kernel(
    float* __restrict__ out, const float* __restrict__ part)
{
  size_t i = (size_t)blockIdx.x * 256 + threadIdx.x;
  float4* o = (float4*)out;
  const float4* p = (const float4*)part;
  float4 a = o[i], b = p[i];
  a.x += b.x; a.y += b.y; a.z += b.z; a.w += b.w;
  o[i] = a;
}

extern "C" void kernel_launch(void* const* d_in, const int* in_sizes, int n_in,
                              void* d_out, int out_size, void* d_ws, size_t ws_size,
                              hipStream_t stream) {
  const float* x     = (const float*)d_in[0];
  const float* grid  = (const float*)d_in[1];
  const float* coeff = (const float*)d_in[2];
  const float* sb    = (const float*)d_in[3];
  const float* ss    = (const float*)d_in[4];
  float* out = (float*)d_out;

  u16* Wt = (u16*)d_ws;
  const size_t wt_bytes   = (size_t)OUT_DIM * KDIM * 2;     // 25.2 MB
  const size_t a_bytes    = (size_t)TOKENS * KDIM * 2;      // 201.3 MB
  const size_t part_bytes = (size_t)TOKENS * OUT_DIM * 4;   // 33.6 MB
  u16*   Abuf = (u16*)((char*)d_ws + wt_bytes);
  float* part = (float*)((char*)d_ws + wt_bytes + a_bytes);

  pack_wt_kernel<<<(OUT_DIM * IN_DIM) / 256, 256, 0, stream>>>(coeff, sb, ss, Wt);

  if (ws_size >= wt_bytes + a_bytes + part_bytes) {
    // split-K=2: 1024 blocks = 4 blocks/CU to fill the barrier-drain stalls
    expand_kernel<<<(TOKENS * IN_DIM) / 256, 256, 0, stream>>>(x, grid, Abuf, 0);
    gemm_kernel<<<64 * 8 * 2, 256, 0, stream>>>(Abuf, Wt, out, part, 0, 64, (KDIM / BK) / 2);
    reduce_kernel<<<(TOKENS * OUT_DIM / 4) / 256, 256, 0, stream>>>(out, part);
  } else {
    // fallback: R4 path (chunked if ws is small)
    size_t avail   = ws_size > wt_bytes ? ws_size - wt_bytes : 0;
    size_t maxrows = avail / ((size_t)KDIM * 2);
    int chunk = (int)(maxrows & ~(size_t)127);
    if (chunk > TOKENS) chunk = TOKENS;
    if (chunk < 128)    chunk = 128;
    for (int m0 = 0; m0 < TOKENS; m0 += chunk) {
      int rows = TOKENS - m0 < chunk ? TOKENS - m0 : chunk;
      expand_kernel<<<(rows * IN_DIM) / 256, 256, 0, stream>>>(x, grid, Abuf, m0);
      gemm_kernel<<<(rows / 128) * 8, 256, 0, stream>>>(Abuf, Wt, out, nullptr, m0, rows / 128, KDIM / BK);
    }
  }
}

// Round 6
// 419.695 us; speedup vs baseline: 1.1717x; 1.1717x over previous
//
#include <hip/hip_runtime.h>
#include <hip/hip_bf16.h>
#include <stdint.h>

typedef __attribute__((ext_vector_type(8))) short short8;
typedef __attribute__((ext_vector_type(16))) float floatx16;
typedef unsigned short u16;

#define IN_DIM  1024
#define OUT_DIM 1024
#define NG      11            // spline bases per channel
#define GK      12            // + silu slot
#define KDIM    (IN_DIM * GK) // 12288
#define TOKENS  8192
#define BK      64            // K-tile: 4 mfma k-steps (32x32x16)

__device__ __forceinline__ u16 f2bf(float f) {
  uint32_t u = __float_as_uint(f);
  uint32_t r = (u + 0x7fffu + ((u >> 16) & 1u)) >> 16;  // RNE
  return (u16)r;
}

// ---------------- pack Wt: bf16 [OUT_DIM][KDIM] (R5 coalesced version)
__global__ __launch_bounds__(256) void pack_wt_kernel(
    const float* __restrict__ coeff, const float* __restrict__ sb,
    const float* __restrict__ ss_p, u16* __restrict__ Wt)
{
  __shared__ float cf[256 * NG];
  __shared__ __align__(16) u16 st[256 * GK];
  const int tid = threadIdx.x;
  const int b   = blockIdx.x;
  const int o   = b >> 2;
  const int i0  = (b & 3) * 256;
  const float* cbase = coeff + (size_t)o * (IN_DIM * NG) + (size_t)i0 * NG;
#pragma unroll
  for (int p = 0; p < NG; ++p) cf[p * 256 + tid] = cbase[p * 256 + tid];
  const float ss  = ss_p[0];
  const float sbv = sb[(size_t)o * IN_DIM + i0 + tid];
  __syncthreads();
  const float* cp = cf + tid * NG;
  u16 h[GK];
#pragma unroll
  for (int g = 0; g < NG; ++g) h[g] = f2bf(cp[g] * ss);
  h[NG] = f2bf(sbv);
  uint64_t V0 = (uint64_t)h[0] | ((uint64_t)h[1] << 16) | ((uint64_t)h[2] << 32) | ((uint64_t)h[3] << 48);
  uint64_t V1 = (uint64_t)h[4] | ((uint64_t)h[5] << 16) | ((uint64_t)h[6] << 32) | ((uint64_t)h[7] << 48);
  uint64_t V2 = (uint64_t)h[8] | ((uint64_t)h[9] << 16) | ((uint64_t)h[10] << 32) | ((uint64_t)h[11] << 48);
  uint64_t* sp = (uint64_t*)(st + tid * GK);
  sp[0] = V0; sp[1] = V1; sp[2] = V2;
  __syncthreads();
  const uint4* src = (const uint4*)st;
  uint4* dst = (uint4*)(Wt + (size_t)b * (256 * GK));
  dst[tid] = src[tid];
  if (tid < 128) dst[256 + tid] = src[256 + tid];
}

// ---------------- expand (verified R4 version, absmax 0.125)
__global__ __launch_bounds__(256) void expand_kernel(
    const float* __restrict__ X, const float* __restrict__ grid,
    u16* __restrict__ A, int m0)
{
  __shared__ __align__(16) u16 st[256 * GK];
  int tid = threadIdx.x;
  int idx = blockIdx.x * 256 + tid;
  float x = X[(size_t)m0 * IN_DIM + idx];

  const float g0    = grid[0];
  const float inv_h = 1.0f / (grid[1] - grid[0]);

  float t  = (x - g0) * inv_h;
  float fc = floorf(t);
  int   c  = (int)fc;
  float u  = t - fc;
  float u2 = u * u;
  float w1 = 1.0f - u;
  float b0 = (w1 * w1 * w1) * (1.0f / 6.0f);
  float b1 = (0.5f * u - 1.0f) * u2 + (2.0f / 3.0f);
  float b2 = ((-0.5f * u + 0.5f) * u + 0.5f) * u + (1.0f / 6.0f);
  float b3 = (u2 * u) * (1.0f / 6.0f);
  float sil = x / (1.0f + __expf(-x));

  uint64_t P = (uint64_t)f2bf(b0) | ((uint64_t)f2bf(b1) << 16)
             | ((uint64_t)f2bf(b2) << 32) | ((uint64_t)f2bf(b3) << 48);
  int  k  = c - 3;
  bool cv = (c >= 0) && (c <= 13);
  int  kneg = (k < 0) ? -k : 0;
  uint64_t Pc = cv ? (P >> (16 * kneg)) : 0ull;
  uint32_t sh = (uint32_t)(16 * ((k < 0) ? 0 : k));

  uint64_t V0 = (sh < 64)  ? (Pc << (sh & 63)) : 0ull;
  uint64_t V1 = (sh == 0)  ? 0ull :
                (sh < 64)  ? (Pc >> ((64 - sh) & 63)) :
                (sh < 128) ? (Pc << ((sh - 64) & 63)) : 0ull;
  uint64_t V2 = (sh <= 64) ? 0ull :
                (sh < 128) ? (Pc >> ((128 - sh) & 63)) :
                             (Pc << ((sh - 128) & 63));
  V2 = (V2 & 0x0000FFFFFFFFFFFFull) | ((uint64_t)f2bf(sil) << 48);

  uint64_t* sp = (uint64_t*)(st + tid * GK);
  sp[0] = V0; sp[1] = V1; sp[2] = V2;
  __syncthreads();

  const uint4* src = (const uint4*)st;
  uint4* dst = (uint4*)(A + (size_t)blockIdx.x * (256 * GK));
  dst[tid] = src[tid];
  if (tid < 128) dst[256 + tid] = src[256 + tid];
}

// ---------------- GEMM: 32x32x16 MFMA, 128-reg bucket -> 4 blocks/CU
__device__ __forceinline__ void async16(const u16* g, u16* l) {
  __builtin_amdgcn_global_load_lds(
      (const __attribute__((address_space(1))) uint32_t*)g,
      (__attribute__((address_space(3))) uint32_t*)l,
      16, 0, 0);
}

// blockIdx ≡ bm (mod 8) -> A-strip XCD-local (R4-verified: FETCH 197 MB).
// Wave = 64x64 tile = 2x2 of 32x32x16 MFMA: acc 64 AGPR, frags 16 VGPR/k-step.
// __launch_bounds__(256,4): cap 128 regs/wave -> 4 waves/SIMD (R5 post-mortem: 152 regs
// landed in the 256-bucket -> 2 waves/SIMD, the occupancy pin).
__global__ __launch_bounds__(256, 4) void gemm_kernel(
    const u16* __restrict__ A, const u16* __restrict__ Wt,
    float* __restrict__ out, int m0, int mtiles)
{
  __shared__ __align__(16) u16 As[128 * BK];   // 16 KB
  __shared__ __align__(16) u16 Bs[128 * BK];   // 16 KB

  const int tid  = threadIdx.x;
  const int lane = tid & 63;
  const int wave = tid >> 6;
  const int bm   = blockIdx.x % mtiles;
  const int bn   = blockIdx.x / mtiles;
  const int wm = (wave >> 1) * 64;
  const int wn = (wave & 1) * 64;

  floatx16 acc[2][2];
#pragma unroll
  for (int a = 0; a < 2; ++a)
#pragma unroll
    for (int b = 0; b < 2; ++b)
#pragma unroll
      for (int r = 0; r < 16; ++r) acc[a][b][r] = 0.f;

  // Staging (R2-verified XOR swizzle, zero conflicts): chunk c of row r at slot c^(r&7)
  const int srow  = lane >> 3;
  const int gamma = (lane & 7) ^ srow;
  const u16* Ag = A  + (size_t)(bm * 128 + wave * 32 + srow) * KDIM + gamma * 8;
  const u16* Bg = Wt + (size_t)(bn * 128 + wave * 32 + srow) * KDIM + gamma * 8;
  u16* Al = As + (wave * 32) * BK;
  u16* Bl = Bs + (wave * 32) * BK;

  // Read-side: 32x32x16 A-operand A[m=lane&31][k=(lane>>5)*8+j]
  const int l31 = lane & 31;
  const int g   = lane >> 5;         // k-half
  const int sw  = lane & 7;          // row&7 (wm, s*32 are multiples of 8)

  for (int k0 = 0; k0 < KDIM; k0 += BK) {
#pragma unroll
    for (int op = 0; op < 4; ++op) {
      async16(Ag + k0 + (size_t)(op * 8) * KDIM, Al + op * 8 * BK);
      async16(Bg + k0 + (size_t)(op * 8) * KDIM, Bl + op * 8 * BK);
    }
    __syncthreads();

#pragma unroll
    for (int t = 0; t < 4; ++t) {        // 4 k-steps of 16
      const int cc = (t * 2 + g) ^ sw;   // 16B chunk index, swizzled
      short8 af[2], bf[2];
#pragma unroll
      for (int s = 0; s < 2; ++s) {
        af[s] = *(const short8*)&As[(wm + s * 32 + l31) * BK + cc * 8];
        bf[s] = *(const short8*)&Bs[(wn + s * 32 + l31) * BK + cc * 8];
      }
#pragma unroll
      for (int sm = 0; sm < 2; ++sm)
#pragma unroll
        for (int sn = 0; sn < 2; ++sn)
          acc[sm][sn] = __builtin_amdgcn_mfma_f32_32x32x16_bf16(af[sm], bf[sn], acc[sm][sn], 0, 0, 0);
    }

    __syncthreads();
  }

  // C/D map (m74/m101-verified): col=lane&31, row=(reg&3)+8*(reg>>2)+4*(lane>>5)
#pragma unroll
  for (int sm = 0; sm < 2; ++sm)
#pragma unroll
    for (int sn = 0; sn < 2; ++sn) {
      const int row0 = m0 + bm * 128 + wm + sm * 32 + 4 * g;
      const int col  = bn * 128 + wn + sn * 32 + l31;
#pragma unroll
      for (int reg = 0; reg < 16; ++reg) {
        int row = row0 + (reg & 3) + 8 * (reg >> 2);
        out[(size_t)row * OUT_DIM + col] = acc[sm][sn][reg];
      }
    }
}

extern "C" void kernel_launch(void* const* d_in, const int* in_sizes, int n_in,
                              void* d_out, int out_size, void* d_ws, size_t ws_size,
                              hipStream_t stream) {
  const float* x     = (const float*)d_in[0];
  const float* grid  = (const float*)d_in[1];
  const float* coeff = (const float*)d_in[2];
  const float* sb    = (const float*)d_in[3];
  const float* ss    = (const float*)d_in[4];
  float* out = (float*)d_out;

  u16* Wt = (u16*)d_ws;
  const size_t wt_bytes = (size_t)OUT_DIM * KDIM * 2;   // 25.2 MB
  u16* Abuf = (u16*)((char*)d_ws + wt_bytes);

  size_t avail   = ws_size > wt_bytes ? ws_size - wt_bytes : 0;
  size_t maxrows = avail / ((size_t)KDIM * 2);
  int chunk = (int)(maxrows & ~(size_t)127);
  if (chunk > TOKENS) chunk = TOKENS;
  if (chunk < 128)    chunk = 128;

  pack_wt_kernel<<<(OUT_DIM * IN_DIM) / 256, 256, 0, stream>>>(coeff, sb, ss, Wt);

  for (int m0 = 0; m0 < TOKENS; m0 += chunk) {
    int rows = TOKENS - m0 < chunk ? TOKENS - m0 : chunk;   // multiple of 128
    expand_kernel<<<(rows * IN_DIM) / 256, 256, 0, stream>>>(x, grid, Abuf, m0);
    gemm_kernel<<<(rows / 128) * 8, 256, 0, stream>>>(Abuf, Wt, out, m0, rows / 128);
  }
}

// Round 7
// 413.041 us; speedup vs baseline: 1.1905x; 1.0161x over previous
//
#include <hip/hip_runtime.h>
#include <hip/hip_bf16.h>
#include <stdint.h>

typedef __attribute__((ext_vector_type(8))) short short8;
typedef __attribute__((ext_vector_type(16))) float floatx16;
typedef unsigned short u16;

#define IN_DIM  1024
#define OUT_DIM 1024
#define NG      11            // spline bases per channel
#define GK      12            // + silu slot
#define KDIM    (IN_DIM * GK) // 12288
#define TOKENS  8192
#define BK      64            // K-tile: 4 mfma k-steps (32x32x16)

__device__ __forceinline__ u16 f2bf(float f) {
  uint32_t u = __float_as_uint(f);
  uint32_t r = (u + 0x7fffu + ((u >> 16) & 1u)) >> 16;  // RNE
  return (u16)r;
}

// ---------------- pack Wt: bf16 [OUT_DIM][KDIM] (R5 coalesced version)
__global__ __launch_bounds__(256) void pack_wt_kernel(
    const float* __restrict__ coeff, const float* __restrict__ sb,
    const float* __restrict__ ss_p, u16* __restrict__ Wt)
{
  __shared__ float cf[256 * NG];
  __shared__ __align__(16) u16 st[256 * GK];
  const int tid = threadIdx.x;
  const int b   = blockIdx.x;
  const int o   = b >> 2;
  const int i0  = (b & 3) * 256;
  const float* cbase = coeff + (size_t)o * (IN_DIM * NG) + (size_t)i0 * NG;
#pragma unroll
  for (int p = 0; p < NG; ++p) cf[p * 256 + tid] = cbase[p * 256 + tid];
  const float ss  = ss_p[0];
  const float sbv = sb[(size_t)o * IN_DIM + i0 + tid];
  __syncthreads();
  const float* cp = cf + tid * NG;
  u16 h[GK];
#pragma unroll
  for (int g = 0; g < NG; ++g) h[g] = f2bf(cp[g] * ss);
  h[NG] = f2bf(sbv);
  uint64_t V0 = (uint64_t)h[0] | ((uint64_t)h[1] << 16) | ((uint64_t)h[2] << 32) | ((uint64_t)h[3] << 48);
  uint64_t V1 = (uint64_t)h[4] | ((uint64_t)h[5] << 16) | ((uint64_t)h[6] << 32) | ((uint64_t)h[7] << 48);
  uint64_t V2 = (uint64_t)h[8] | ((uint64_t)h[9] << 16) | ((uint64_t)h[10] << 32) | ((uint64_t)h[11] << 48);
  uint64_t* sp = (uint64_t*)(st + tid * GK);
  sp[0] = V0; sp[1] = V1; sp[2] = V2;
  __syncthreads();
  const uint4* src = (const uint4*)st;
  uint4* dst = (uint4*)(Wt + (size_t)b * (256 * GK));
  dst[tid] = src[tid];
  if (tid < 128) dst[256 + tid] = src[256 + tid];
}

// ---------------- expand (verified R4 version, absmax 0.125)
__global__ __launch_bounds__(256) void expand_kernel(
    const float* __restrict__ X, const float* __restrict__ grid,
    u16* __restrict__ A, int m0)
{
  __shared__ __align__(16) u16 st[256 * GK];
  int tid = threadIdx.x;
  int idx = blockIdx.x * 256 + tid;
  float x = X[(size_t)m0 * IN_DIM + idx];

  const float g0    = grid[0];
  const float inv_h = 1.0f / (grid[1] - grid[0]);

  float t  = (x - g0) * inv_h;
  float fc = floorf(t);
  int   c  = (int)fc;
  float u  = t - fc;
  float u2 = u * u;
  float w1 = 1.0f - u;
  float b0 = (w1 * w1 * w1) * (1.0f / 6.0f);
  float b1 = (0.5f * u - 1.0f) * u2 + (2.0f / 3.0f);
  float b2 = ((-0.5f * u + 0.5f) * u + 0.5f) * u + (1.0f / 6.0f);
  float b3 = (u2 * u) * (1.0f / 6.0f);
  float sil = x / (1.0f + __expf(-x));

  uint64_t P = (uint64_t)f2bf(b0) | ((uint64_t)f2bf(b1) << 16)
             | ((uint64_t)f2bf(b2) << 32) | ((uint64_t)f2bf(b3) << 48);
  int  k  = c - 3;
  bool cv = (c >= 0) && (c <= 13);
  int  kneg = (k < 0) ? -k : 0;
  uint64_t Pc = cv ? (P >> (16 * kneg)) : 0ull;
  uint32_t sh = (uint32_t)(16 * ((k < 0) ? 0 : k));

  uint64_t V0 = (sh < 64)  ? (Pc << (sh & 63)) : 0ull;
  uint64_t V1 = (sh == 0)  ? 0ull :
                (sh < 64)  ? (Pc >> ((64 - sh) & 63)) :
                (sh < 128) ? (Pc << ((sh - 64) & 63)) : 0ull;
  uint64_t V2 = (sh <= 64) ? 0ull :
                (sh < 128) ? (Pc >> ((128 - sh) & 63)) :
                             (Pc << ((sh - 128) & 63));
  V2 = (V2 & 0x0000FFFFFFFFFFFFull) | ((uint64_t)f2bf(sil) << 48);

  uint64_t* sp = (uint64_t*)(st + tid * GK);
  sp[0] = V0; sp[1] = V1; sp[2] = V2;
  __syncthreads();

  const uint4* src = (const uint4*)st;
  uint4* dst = (uint4*)(A + (size_t)blockIdx.x * (256 * GK));
  dst[tid] = src[tid];
  if (tid < 128) dst[256 + tid] = src[256 + tid];
}

// ---------------- GEMM: 32x32x16 MFMA (128-reg bucket) + split-K (grid 4 blocks/CU)
__device__ __forceinline__ void async16(const u16* g, u16* l) {
  __builtin_amdgcn_global_load_lds(
      (const __attribute__((address_space(1))) uint32_t*)g,
      (__attribute__((address_space(3))) uint32_t*)l,
      16, 0, 0);
}

// grid = mtiles*8*nsplit; split s covers K range [s*k_iters*BK, ...); s=0 -> out, s=1 -> part.
// blockIdx ≡ bm (mod 8) for all (bn,s) -> A-strip XCD-local (R4: FETCH 197 MB, conflicts 0).
// R5+R6 post-mortems: occupancy needs BOTH regs<=128 (32x32 path, R6: VGPR 64 + AGPR 64)
// AND grid >= 1024 (split-K). Each alone left 2 blocks/CU.
__global__ __launch_bounds__(256, 4) void gemm_kernel(
    const u16* __restrict__ A, const u16* __restrict__ Wt,
    float* __restrict__ out, float* __restrict__ part,
    int m0, int mtiles, int k_iters)
{
  __shared__ __align__(16) u16 As[128 * BK];   // 16 KB
  __shared__ __align__(16) u16 Bs[128 * BK];   // 16 KB

  const int tid  = threadIdx.x;
  const int lane = tid & 63;
  const int wave = tid >> 6;
  const int mt8  = mtiles * 8;
  const int s    = blockIdx.x / mt8;
  const int r    = blockIdx.x - s * mt8;
  const int bm   = r % mtiles;
  const int bn   = r / mtiles;
  const int kb   = s * k_iters * BK;
  const int wm = (wave >> 1) * 64;
  const int wn = (wave & 1) * 64;

  floatx16 acc[2][2];
#pragma unroll
  for (int a = 0; a < 2; ++a)
#pragma unroll
    for (int b = 0; b < 2; ++b)
#pragma unroll
      for (int rr = 0; rr < 16; ++rr) acc[a][b][rr] = 0.f;

  // Staging (R2-verified XOR swizzle, zero conflicts): chunk c of row r at slot c^(r&7)
  const int srow  = lane >> 3;
  const int gamma = (lane & 7) ^ srow;
  const u16* Ag = A  + (size_t)(bm * 128 + wave * 32 + srow) * KDIM + kb + gamma * 8;
  const u16* Bg = Wt + (size_t)(bn * 128 + wave * 32 + srow) * KDIM + kb + gamma * 8;
  u16* Al = As + (wave * 32) * BK;
  u16* Bl = Bs + (wave * 32) * BK;

  // Read-side: 32x32x16 A-operand A[m=lane&31][k=(lane>>5)*8+j]
  const int l31 = lane & 31;
  const int g   = lane >> 5;         // k-half
  const int sw  = lane & 7;          // row&7 (wm, s*32 are multiples of 8)

  for (int it = 0; it < k_iters; ++it) {
    const int k0 = it * BK;
#pragma unroll
    for (int op = 0; op < 4; ++op) {
      async16(Ag + k0 + (size_t)(op * 8) * KDIM, Al + op * 8 * BK);
      async16(Bg + k0 + (size_t)(op * 8) * KDIM, Bl + op * 8 * BK);
    }
    __syncthreads();

#pragma unroll
    for (int t = 0; t < 4; ++t) {        // 4 k-steps of 16
      const int cc = (t * 2 + g) ^ sw;   // 16B chunk index, swizzled
      short8 af[2], bf[2];
#pragma unroll
      for (int ss = 0; ss < 2; ++ss) {
        af[ss] = *(const short8*)&As[(wm + ss * 32 + l31) * BK + cc * 8];
        bf[ss] = *(const short8*)&Bs[(wn + ss * 32 + l31) * BK + cc * 8];
      }
#pragma unroll
      for (int sm = 0; sm < 2; ++sm)
#pragma unroll
        for (int sn = 0; sn < 2; ++sn)
          acc[sm][sn] = __builtin_amdgcn_mfma_f32_32x32x16_bf16(af[sm], bf[sn], acc[sm][sn], 0, 0, 0);
    }

    __syncthreads();
  }

  // C/D map (m74/m101-verified): col=lane&31, row=(reg&3)+8*(reg>>2)+4*(lane>>5)
  float* op = (s == 0) ? out : part;
#pragma unroll
  for (int sm = 0; sm < 2; ++sm)
#pragma unroll
    for (int sn = 0; sn < 2; ++sn) {
      const int row0 = m0 + bm * 128 + wm + sm * 32 + 4 * g;
      const int col  = bn * 128 + wn + sn * 32 + l31;
#pragma unroll
      for (int reg = 0; reg < 16; ++reg) {
        int row = row0 + (reg & 3) + 8 * (reg >> 2);
        op[(size_t)row * OUT_DIM + col] = acc[sm][sn][reg];
      }
    }
}

// out += part, float4-vectorized
__global__ __launch_bounds__(256) void reduce_kernel(
    float* __restrict__ out, const float* __restrict__ part)
{
  size_t i = (size_t)blockIdx.x * 256 + threadIdx.x;
  float4* o = (float4*)out;
  const float4* p = (const float4*)part;
  float4 a = o[i], b = p[i];
  a.x += b.x; a.y += b.y; a.z += b.z; a.w += b.w;
  o[i] = a;
}

extern "C" void kernel_launch(void* const* d_in, const int* in_sizes, int n_in,
                              void* d_out, int out_size, void* d_ws, size_t ws_size,
                              hipStream_t stream) {
  const float* x     = (const float*)d_in[0];
  const float* grid  = (const float*)d_in[1];
  const float* coeff = (const float*)d_in[2];
  const float* sb    = (const float*)d_in[3];
  const float* ss    = (const float*)d_in[4];
  float* out = (float*)d_out;

  u16* Wt = (u16*)d_ws;
  const size_t wt_bytes   = (size_t)OUT_DIM * KDIM * 2;     // 25.2 MB
  const size_t a_bytes    = (size_t)TOKENS * KDIM * 2;      // 201.3 MB
  const size_t part_bytes = (size_t)TOKENS * OUT_DIM * 4;   // 33.6 MB
  u16*   Abuf = (u16*)((char*)d_ws + wt_bytes);
  float* part = (float*)((char*)d_ws + wt_bytes + a_bytes);

  pack_wt_kernel<<<(OUT_DIM * IN_DIM) / 256, 256, 0, stream>>>(coeff, sb, ss, Wt);

  if (ws_size >= wt_bytes + a_bytes + part_bytes) {
    // split-K=2: 1024 blocks = 4 blocks/CU (regs 128/wave via 32x32 path, LDS 32KBx4=128<=160)
    expand_kernel<<<(TOKENS * IN_DIM) / 256, 256, 0, stream>>>(x, grid, Abuf, 0);
    gemm_kernel<<<64 * 8 * 2, 256, 0, stream>>>(Abuf, Wt, out, part, 0, 64, (KDIM / BK) / 2);
    reduce_kernel<<<(TOKENS * OUT_DIM / 4) / 256, 256, 0, stream>>>(out, part);
  } else {
    // fallback: chunked, full-K (nsplit=1; s==0 always -> writes out directly)
    size_t avail   = ws_size > wt_bytes ? ws_size - wt_bytes : 0;
    size_t maxrows = avail / ((size_t)KDIM * 2);
    int chunk = (int)(maxrows & ~(size_t)127);
    if (chunk > TOKENS) chunk = TOKENS;
    if (chunk < 128)    chunk = 128;
    for (int m0 = 0; m0 < TOKENS; m0 += chunk) {
      int rows = TOKENS - m0 < chunk ? TOKENS - m0 : chunk;
      expand_kernel<<<(rows * IN_DIM) / 256, 256, 0, stream>>>(x, grid, Abuf, m0);
      gemm_kernel<<<(rows / 128) * 8, 256, 0, stream>>>(Abuf, Wt, out, nullptr, m0, rows / 128, KDIM / BK);
    }
  }
}